// Round 12
// baseline (1201.138 us; speedup 1.0000x reference)
//
#include <hip/hip_runtime.h>
#include <hip/hip_bf16.h>
#include <hip/hip_fp16.h>
#include <cstdint>
#include <cstddef>

#define NB   131072   // items
#define ED   256      // e_dim
#define NQL  4        // levels
#define NEC  256      // codebook entries

typedef _Float16 f16;
typedef f16  f16x8 __attribute__((ext_vector_type(8)));
typedef float f32x4 __attribute__((ext_vector_type(4)));

static constexpr float FMAXV = 3.402823466e+38f;
static constexpr float TAUH  = 0.078125f;   // rescore gate on approx top-2 gap, d/2 units

static constexpr size_t OFF_REC  = (size_t)NB * ED;
static constexpr size_t OFF_LOSS = 2 * (size_t)NB * ED;
static constexpr size_t OFF_SIDX = OFF_LOSS + 1;
static constexpr size_t OFF_RIDX = OFF_SIDX + (size_t)NB * NQL;

// workspace layout (bytes)
static constexpr size_t WS_LOSS = 0;                      // 8 doubles
static constexpr size_t WS_NORM = 256;                    // 8*256 f32 (norm - 256)
static constexpr size_t WS_CBH  = 256 + 8 * 256 * 4;      // 8448; 8*256*256 f16 (1 MB)

// ---- prep: zero loss accumulators + codebook row norms (pre-shifted by -256) ----
__global__ void kPrep(const float* __restrict__ cbS, const float* __restrict__ cbR,
                      float* __restrict__ norms, double* __restrict__ lossAcc) {
  const int cbi = blockIdx.x;    // 0..7
  const int j   = threadIdx.x;   // 0..255
  if (cbi == 0 && j < 8) lossAcc[j] = 0.0;
  const float* row = (cbi < 4 ? cbS : cbR) + ((size_t)(cbi & 3) * NEC + j) * ED;
  float acc = 0.f;
  for (int k = 0; k < ED; k += 4) {
    float4 v = *(const float4*)(row + k);
    acc += v.x * v.x + v.y * v.y + v.z * v.z + v.w * v.w;
  }
  norms[cbi * NEC + j] = acc - 256.0f;   // exact shift (Sterbenz range)
}

// ---- NEGATED f16 copy of codebooks: acc = 0.5*nrm + sum(-c)*r = d/2 ----
__global__ void kConvH(const float* __restrict__ cbS, const float* __restrict__ cbR,
                       f16* __restrict__ cbH) {
  const int f   = blockIdx.x * 256 + threadIdx.x;   // 0..524287
  const int cbi = f >> 16;
  const int rem = f & 65535;
  const float v = (cbi < 4 ? cbS + ((size_t)cbi << 16) : cbR + ((size_t)(cbi - 4) << 16))[rem];
  cbH[f] = (f16)(-v);   // RTN, negated
}

// packed key helpers: low 8 mantissa bits carry the codeword index
__device__ __forceinline__ float pk(float v, int j) {
  return __uint_as_float((__float_as_uint(v) & ~255u) | (unsigned)j);
}
__device__ __forceinline__ float unpv(float k) {
  return __uint_as_float(__float_as_uint(k) & ~255u);
}
__device__ __forceinline__ void ins3(float& s0, float& s1, float& s2, float k) {
  float t0 = fmaxf(s0, k); s0 = fminf(s0, k);
  float t1 = fmaxf(s1, t0); s1 = fminf(s1, t0);
  s2 = fminf(s2, t1);
}
__device__ __forceinline__ void mrg3(float& a0, float& a1, float& a2,
                                     float b0, float b1, float b2) {
  float x  = fmaxf(a0, b0);
  float c0 = fminf(a0, b0);
  float m1 = fminf(a1, b1), M1 = fmaxf(a1, b1);
  float c1 = fminf(fminf(x, a1), b1);
  float c2 = fminf(fminf(fmaxf(x, m1), M1), fminf(a2, b2));
  a0 = c0; a1 = c1; a2 = c2;
}

// ---- main fused RVQ kernel: 2-wave blocks, 16 items, 6 chains/CU ----
// Each wave scores 128 codewords in TWO passes of 64 (r11 bug: single pass
// covered only j<128 block-wide -> wrong argmins). acc[4]=16 AGPR reused per
// pass; Bf[4]=16 VGPR; res[32] -> ~75 arch regs <= 84-cap at 3 waves/SIMD.
// 12 waves/CU = 6 independent chains; d/2 trick (0.5*nrm init, negated cbH).
__global__ __launch_bounds__(128, 3)
void kMain16(const float* __restrict__ x,
             const float* __restrict__ cbS,
             const float* __restrict__ cbR,
             const f16*  __restrict__ cbH,
             const float* __restrict__ norms,
             double* __restrict__ lossAcc,
             float* __restrict__ out) {
  __shared__ __align__(16) char   RhBuf[16 * 512];   // 16 items x 512B f16 (8 KB)
  __shared__ __align__(16) float4 keybuf[16][2];     // per-wave top-3 per item
  __shared__ float redS[2];

  const int tid  = threadIdx.x;     // 0..127
  const int lane = tid & 63;
  const int w    = tid >> 6;        // wave 0,1
  const int it_o = tid >> 3;        // owner item 0..15 (8 threads/item)
  const int kg   = tid & 7;         // k-chunk (32 floats)
  const int l15  = lane & 15;       // item in GEMM view
  const int l4   = lane >> 4;       // k-slot / j-subgroup
  const int br   = blockIdx.y;
  const int g0   = blockIdx.x * 16;

  const float* cbf32base = br ? cbR : cbS;
  float res[32];
  float lossReg = 0.f;

  // ---- load residual = x[:, br*E .. br*E+E) slice (32 f32/thread) ----
  {
    const float* xp = x + (size_t)(g0 + it_o) * (2 * ED) + br * ED + kg * 32;
#pragma unroll
    for (int i = 0; i < 8; ++i) {
      float4 v = *(const float4*)(xp + 4 * i);
      res[4 * i + 0] = v.x; res[4 * i + 1] = v.y;
      res[4 * i + 2] = v.z; res[4 * i + 3] = v.w;
    }
  }

#pragma unroll 1
  for (int lev = 0; lev < NQL; ++lev) {
    const int cbi = br * 4 + lev;
    const float* nrm = norms + (size_t)cbi * NEC;
    const f16*   cbh = cbH + ((size_t)cbi << 16);
    const float* cbf32 = cbf32base + (size_t)lev * NEC * ED;

    // ---- stage Rh (f16, own item's 64B slice), XOR swizzle on FULL offset ----
#pragma unroll
    for (int c = 0; c < 4; ++c) {
      f16x8 h;
#pragma unroll
      for (int u = 0; u < 8; ++u) h[u] = (f16)res[c * 8 + u];
      int off = it_o * 512 + kg * 64 + c * 16;
      off ^= (it_o & 7) << 4;
      *(f16x8*)&RhBuf[off] = h;
    }
    __syncthreads();   // barrier 1: Rh ready (2-wave barrier, cheap)

    // ---- wave w scores j in {p*128 + w*64 + [0,64)} for p=0,1 ----
    float s0 = FMAXV, s1 = FMAXV, s2 = FMAXV;   // running top-3 packed keys

#pragma unroll 1
    for (int p = 0; p < 2; ++p) {
      const int jbase = p * 128 + w * 64;

      // acc init = 0.5*nrm -> acc_final = d/2 (negated cbH)
      f32x4 acc[4];
#pragma unroll
      for (int nt = 0; nt < 4; ++nt) {
        float4 nv = *(const float4*)&nrm[jbase + nt * 16 + l4 * 4];
        f32x4 h; h[0] = 0.5f * nv.x; h[1] = 0.5f * nv.y;
        h[2] = 0.5f * nv.z; h[3] = 0.5f * nv.w;
        acc[nt] = h;
      }

#pragma unroll 1
      for (int ks = 0; ks < 8; ++ks) {
        const int offA = (l15 * 512 + ks * 64 + l4 * 16) ^ ((l15 & 7) << 4);
        const f16x8 A = *(const f16x8*)&RhBuf[offA];
        f16x8 Bf[4];
#pragma unroll
        for (int nt = 0; nt < 4; ++nt) {
          const int j = jbase + nt * 16 + l15;
          Bf[nt] = *(const f16x8*)&cbh[(size_t)j * ED + ks * 32 + l4 * 8];
        }
#pragma unroll
        for (int nt = 0; nt < 4; ++nt)
          acc[nt] = __builtin_amdgcn_mfma_f32_16x16x32_f16(Bf[nt], A, acc[nt], 0, 0, 0);
      }

      // fold this pass's 16 keys/lane into the running top-3 (item = l15)
#pragma unroll
      for (int nt = 0; nt < 4; ++nt)
#pragma unroll
        for (int r = 0; r < 4; ++r)
          ins3(s0, s1, s2, pk(acc[nt][r], jbase + nt * 16 + l4 * 4 + r));
    }

    // merge the 4 l4-groups (disjoint j-subsets, same item): xor 16, 32
    {
      float b0k = __shfl_xor(s0, 16), b1k = __shfl_xor(s1, 16), b2k = __shfl_xor(s2, 16);
      mrg3(s0, s1, s2, b0k, b1k, b2k);
      b0k = __shfl_xor(s0, 32); b1k = __shfl_xor(s1, 32); b2k = __shfl_xor(s2, 32);
      mrg3(s0, s1, s2, b0k, b1k, b2k);
    }
    if (l4 == 0) { float4 v; v.x = s0; v.y = s1; v.z = s2; v.w = FMAXV;
                   keybuf[l15][w] = v; }
    __syncthreads();   // barrier 2: keybuf ready (also: all GEMM reads of Rh done)

    // ---- merge both waves' triples in the 8-thread owner group ----
    int jm;
    {
      float4 kv = keybuf[it_o][kg & 1];
      float t0 = kv.x, t1 = kv.y, t2 = kv.z;
      float b0k = __shfl_xor(t0, 1), b1k = __shfl_xor(t1, 1), b2k = __shfl_xor(t2, 1);
      mrg3(t0, t1, t2, b0k, b1k, b2k);   // all 8 lanes now hold global top-3
      jm = (int)(__float_as_uint(t0) & 255u);
      const float gap = unpv(t1) - unpv(t0);
      if (gap < TAUH) {   // group-uniform: exact fp32 rescore of top-3
        const int cand[3] = { jm, (int)(__float_as_uint(t1) & 255u),
                                  (int)(__float_as_uint(t2) & 255u) };
        float bestd = FMAXV; int bestj = 0;
#pragma unroll 1
        for (int cc = 0; cc < 3; ++cc) {
          const int j = cand[cc];
          const float* row = cbf32 + (size_t)j * ED + kg * 32;
          float p2 = 0.f;
#pragma unroll
          for (int i = 0; i < 8; ++i) {
            float4 q = *(const float4*)(row + 4 * i);
            p2 = fmaf(res[4 * i + 0], q.x, p2);
            p2 = fmaf(res[4 * i + 1], q.y, p2);
            p2 = fmaf(res[4 * i + 2], q.z, p2);
            p2 = fmaf(res[4 * i + 3], q.w, p2);
          }
          p2 += __shfl_xor(p2, 1);
          p2 += __shfl_xor(p2, 2);
          p2 += __shfl_xor(p2, 4);
          const float d = fmaf(-2.f, p2, nrm[j]);
          if (d < bestd || (d == bestd && j < bestj)) { bestd = d; bestj = j; }
        }
        jm = bestj;
      }
      if (kg == 0) {
        const size_t ioff = (br ? OFF_RIDX : OFF_SIDX) + (size_t)(g0 + it_o) * NQL + lev;
        out[ioff] = (float)jm;
      }
    }

    // ---- residual update + loss (exact reference rounding chain) ----
    {
      const float* crow = cbf32 + (size_t)jm * ED + kg * 32;
#pragma unroll
      for (int i = 0; i < 8; ++i) {
        float4 q = *(const float4*)(crow + 4 * i);
#pragma unroll
        for (int u = 0; u < 4; ++u) {
          float cv = (u == 0 ? q.x : u == 1 ? q.y : u == 2 ? q.z : q.w);
          float r  = res[4 * i + u];
          float dd = cv - r;
          lossReg = fmaf(dd, dd, lossReg);
          float xr = r + dd;      // straight-through x_res
          res[4 * i + u] = r - xr;
        }
      }
    }
  }

  // ---- x_q = x - res_final ----
  {
    const float* xp = x + (size_t)(g0 + it_o) * (2 * ED) + br * ED + kg * 32;
    float* op = out + (br ? OFF_REC : 0) + (size_t)(g0 + it_o) * ED + kg * 32;
#pragma unroll
    for (int i = 0; i < 8; ++i) {
      float4 xv = *(const float4*)(xp + 4 * i);
      float4 o;
      o.x = xv.x - res[4 * i + 0];
      o.y = xv.y - res[4 * i + 1];
      o.z = xv.z - res[4 * i + 2];
      o.w = xv.w - res[4 * i + 3];
      *(float4*)(op + 4 * i) = o;
    }
  }

  // ---- loss: wave reduce + one atomic per block (8 slots to spread contention) ----
#pragma unroll
  for (int d = 1; d < 64; d <<= 1) lossReg += __shfl_xor(lossReg, d);
  if (lane == 0) redS[w] = lossReg;
  __syncthreads();
  if (tid == 0)
    atomicAdd(&lossAcc[blockIdx.x & 7], (double)(redS[0] + redS[1]));
}

// ---- finalize scalar loss ----
__global__ void kFin(const double* __restrict__ lossAcc, float* __restrict__ out) {
  if (blockIdx.x == 0 && threadIdx.x == 0) {
    double s = 0.0;
    for (int l = 0; l < 8; ++l) s += lossAcc[l];
    out[OFF_LOSS] = (float)(s * 1.25 / ((double)NB * ED) / 8.0);
  }
}

extern "C" void kernel_launch(void* const* d_in, const int* in_sizes, int n_in,
                              void* d_out, int out_size, void* d_ws, size_t ws_size,
                              hipStream_t stream) {
  const float* x   = (const float*)d_in[0];
  const float* cbS = (const float*)d_in[1];
  const float* cbR = (const float*)d_in[2];
  float* out = (float*)d_out;
  char*  ws  = (char*)d_ws;

  double* lossAcc = (double*)(ws + WS_LOSS);
  float*  norms   = (float*)(ws + WS_NORM);
  f16*    cbH     = (f16*)(ws + WS_CBH);

  hipLaunchKernelGGL(kPrep,   dim3(8),    dim3(256), 0, stream, cbS, cbR, norms, lossAcc);
  hipLaunchKernelGGL(kConvH,  dim3(2048), dim3(256), 0, stream, cbS, cbR, cbH);
  hipLaunchKernelGGL(kMain16, dim3(NB / 16, 2), dim3(128), 0, stream,
                     x, cbS, cbR, cbH, norms, lossAcc, out);
  hipLaunchKernelGGL(kFin,    dim3(1),    dim3(64),  0, stream, lossAcc, out);
}

// Round 13
// 558.333 us; speedup vs baseline: 2.1513x; 2.1513x over previous
//
#include <hip/hip_runtime.h>
#include <hip/hip_bf16.h>
#include <hip/hip_fp16.h>
#include <cstdint>
#include <cstddef>

#define NB   131072   // items
#define ED   256      // e_dim
#define NQL  4        // levels
#define NEC  256      // codebook entries

typedef _Float16 f16;
typedef f16  f16x8 __attribute__((ext_vector_type(8)));
typedef float f32x4 __attribute__((ext_vector_type(4)));

static constexpr float FMAXV = 3.402823466e+38f;
static constexpr float TAUH  = 0.078125f;   // rescore gate, d/2 units (= TAU/2)

static constexpr size_t OFF_REC  = (size_t)NB * ED;
static constexpr size_t OFF_LOSS = 2 * (size_t)NB * ED;
static constexpr size_t OFF_SIDX = OFF_LOSS + 1;
static constexpr size_t OFF_RIDX = OFF_SIDX + (size_t)NB * NQL;

// workspace layout (bytes)
static constexpr size_t WS_LOSS = 0;                      // 8 doubles
static constexpr size_t WS_NORM = 256;                    // 8*256 f32 (norm - 256)
static constexpr size_t WS_CBH  = 256 + 8 * 256 * 4;      // 8448; 8*256*256 f16 (1 MB)

// ---- prep: zero loss accumulators + codebook row norms (pre-shifted by -256) ----
__global__ void kPrep(const float* __restrict__ cbS, const float* __restrict__ cbR,
                      float* __restrict__ norms, double* __restrict__ lossAcc) {
  const int cbi = blockIdx.x;    // 0..7
  const int j   = threadIdx.x;   // 0..255
  if (cbi == 0 && j < 8) lossAcc[j] = 0.0;
  const float* row = (cbi < 4 ? cbS : cbR) + ((size_t)(cbi & 3) * NEC + j) * ED;
  float acc = 0.f;
  for (int k = 0; k < ED; k += 4) {
    float4 v = *(const float4*)(row + k);
    acc += v.x * v.x + v.y * v.y + v.z * v.z + v.w * v.w;
  }
  norms[cbi * NEC + j] = acc - 256.0f;   // exact shift (Sterbenz range)
}

// ---- NEGATED f16 copy of codebooks: acc = 0.5*nrm + sum(-c)*r = d/2 ----
__global__ void kConvH(const float* __restrict__ cbS, const float* __restrict__ cbR,
                       f16* __restrict__ cbH) {
  const int f   = blockIdx.x * 256 + threadIdx.x;   // 0..524287
  const int cbi = f >> 16;
  const int rem = f & 65535;
  const float v = (cbi < 4 ? cbS + ((size_t)cbi << 16) : cbR + ((size_t)(cbi - 4) << 16))[rem];
  cbH[f] = (f16)(-v);   // RTN, negated
}

// packed key helpers: low 8 mantissa bits carry the codeword index
__device__ __forceinline__ float pk(float v, int j) {
  return __uint_as_float((__float_as_uint(v) & ~255u) | (unsigned)j);
}
__device__ __forceinline__ float unpv(float k) {
  return __uint_as_float(__float_as_uint(k) & ~255u);
}
__device__ __forceinline__ void ins3(float& s0, float& s1, float& s2, float k) {
  float t0 = fmaxf(s0, k); s0 = fminf(s0, k);
  float t1 = fmaxf(s1, t0); s1 = fminf(s1, t0);
  s2 = fminf(s2, t1);
}
__device__ __forceinline__ void mrg3(float& a0, float& a1, float& a2,
                                     float b0, float b1, float b2) {
  float x  = fmaxf(a0, b0);
  float c0 = fminf(a0, b0);
  float m1 = fminf(a1, b1), M1 = fmaxf(a1, b1);
  float c1 = fminf(fminf(x, a1), b1);
  float c2 = fminf(fminf(fmaxf(x, m1), M1), fminf(a2, b2));
  a0 = c0; a1 = c1; a2 = c2;
}

// ---- main fused RVQ kernel: r6 structure (64 items, acc[4][4], 16 MFMA/batch)
// + branch-split blocks (gridDim.y=2, 4-level chains), d/2 trick (no fmaf in
// fold), explicit 2-deep A/B pipeline (next batch's loads issue before current
// batch's MFMAs), setprio around MFMA clusters. bounds(256,2): ~220 regs fits.
__global__ __launch_bounds__(256, 2)
void kMain(const float* __restrict__ x,
           const float* __restrict__ cbS,
           const float* __restrict__ cbR,
           const f16*  __restrict__ cbH,
           const float* __restrict__ norms,
           double* __restrict__ lossAcc,
           float* __restrict__ out) {
  __shared__ __align__(16) char  RhBuf[64 * 512];      // f16 residual image (32 KB)
  __shared__ __align__(16) float keybuf[64][4][4];     // per-wave top-3 per item (4 KB)
  __shared__ float redS[4];

  const int tid   = threadIdx.x;
  const int lane  = tid & 63;
  const int w     = tid >> 6;       // wave: owns codewords [64w, 64w+64)
  const int it_o  = tid >> 2;       // owner item 0..63
  const int kq    = tid & 3;        // owner k-quarter
  const int b0    = blockIdx.x * 64;
  const int br    = blockIdx.y;     // branch (src/rec) — one 4-level chain/block
  const int l15   = lane & 15;
  const int l4    = lane >> 4;

  const float* cbf32base = br ? cbR : cbS;
  float res[64];
  float lossA = 0.f, lossB = 0.f;

  // ---- load residual = x[:, br*E .. br*E+E) slice into registers ----
  {
    const float* xp = x + (size_t)(b0 + it_o) * (2 * ED) + br * ED + kq * 64;
#pragma unroll
    for (int i = 0; i < 16; ++i) {
      float4 v = *(const float4*)(xp + 4 * i);
      res[4 * i + 0] = v.x; res[4 * i + 1] = v.y;
      res[4 * i + 2] = v.z; res[4 * i + 3] = v.w;
    }
  }

#pragma unroll 1
  for (int lev = 0; lev < NQL; ++lev) {
    const int cbi = br * 4 + lev;
    const float* nrm = norms + (size_t)cbi * NEC;
    const f16*   cbh = cbH + ((size_t)cbi << 16);
    const float* cbf32 = cbf32base + (size_t)lev * NEC * ED;

    // ---- stage res -> Rh (f16, RTN), swizzled rows of 512B ----
#pragma unroll
    for (int c = 0; c < 8; ++c) {
      f16x8 h;
#pragma unroll
      for (int u = 0; u < 8; ++u) h[u] = (f16)res[c * 8 + u];
      int off = it_o * 512 + kq * 128 + c * 16;
      off ^= (it_o & 7) << 4;
      *(f16x8*)&RhBuf[off] = h;
    }
    __syncthreads();   // barrier 1: Rh ready

    // ---- acc init = 0.5*nrm -> acc_final = d/2 (negated cbH) ----
    f32x4 acc[4][4];
#pragma unroll
    for (int nt = 0; nt < 4; ++nt) {
      float4 nv = *(const float4*)&nrm[w * 64 + nt * 16 + l4 * 4];
      f32x4 h; h[0] = 0.5f * nv.x; h[1] = 0.5f * nv.y;
      h[2] = 0.5f * nv.z; h[3] = 0.5f * nv.w;
#pragma unroll
      for (int mt = 0; mt < 4; ++mt) acc[mt][nt] = h;
    }

    // ---- GEMM: 64x64 tile/wave, 2-deep ping-pong pipeline ----
    f16x8 A0[4], B0[4], A1[4], B1[4];
#define LOADA(Adst, ks_)                                                        \
    {                                                                           \
      _Pragma("unroll")                                                         \
      for (int mt = 0; mt < 4; ++mt) {                                          \
        const int it = mt * 16 + l15;                                           \
        const int offA = (it * 512 + (ks_) * 64 + l4 * 16) ^ ((it & 7) << 4);   \
        Adst[mt] = *(const f16x8*)&RhBuf[offA];                                 \
      }                                                                         \
    }
#define LOADB(Bdst, ks_)                                                        \
    {                                                                           \
      _Pragma("unroll")                                                         \
      for (int nt = 0; nt < 4; ++nt) {                                          \
        const int j = w * 64 + nt * 16 + l15;                                   \
        Bdst[nt] = *(const f16x8*)&cbh[(size_t)j * ED + (ks_) * 32 + l4 * 8];   \
      }                                                                         \
    }
#define MFMA16(Aop, Bop)                                                        \
    {                                                                           \
      __builtin_amdgcn_s_setprio(1);                                            \
      _Pragma("unroll")                                                         \
      for (int mt = 0; mt < 4; ++mt)                                            \
        _Pragma("unroll")                                                       \
        for (int nt = 0; nt < 4; ++nt)                                          \
          acc[mt][nt] = __builtin_amdgcn_mfma_f32_16x16x32_f16(                 \
              Bop[nt], Aop[mt], acc[mt][nt], 0, 0, 0);                          \
      __builtin_amdgcn_s_setprio(0);                                            \
    }

    LOADA(A0, 0); LOADB(B0, 0);
#pragma unroll 1
    for (int ks2 = 0; ks2 < 4; ++ks2) {
      LOADA(A1, 2 * ks2 + 1); LOADB(B1, 2 * ks2 + 1);   // issue next batch first
      MFMA16(A0, B0);
      if (ks2 < 3) { LOADA(A0, 2 * ks2 + 2); LOADB(B0, 2 * ks2 + 2); }
      MFMA16(A1, B1);
    }
#undef LOADA
#undef LOADB
#undef MFMA16

    // ---- argmin: lane holds 16 j-keys (nt x r) for item = mt*16+l15 ----
#pragma unroll
    for (int mt = 0; mt < 4; ++mt) {
      float s0 = FMAXV, s1 = FMAXV, s2 = FMAXV;
#pragma unroll
      for (int nt = 0; nt < 4; ++nt)
#pragma unroll
        for (int r = 0; r < 4; ++r)
          ins3(s0, s1, s2, pk(acc[mt][nt][r], w * 64 + nt * 16 + l4 * 4 + r));
      // merge the 4 l4-groups (disjoint j-subsets, same item): xor 16, 32
      {
        float b0k = __shfl_xor(s0, 16), b1k = __shfl_xor(s1, 16), b2k = __shfl_xor(s2, 16);
        mrg3(s0, s1, s2, b0k, b1k, b2k);
        b0k = __shfl_xor(s0, 32); b1k = __shfl_xor(s1, 32); b2k = __shfl_xor(s2, 32);
        mrg3(s0, s1, s2, b0k, b1k, b2k);
      }
      if (l4 == 0) {   // lanes 0..15 write item mt*16+l15
        float4 v; v.x = s0; v.y = s1; v.z = s2; v.w = FMAXV;
        *(float4*)&keybuf[mt * 16 + l15][w][0] = v;
      }
    }
    __syncthreads();   // barrier 2: keybuf ready (also: all Rh reads done)

    // ---- cross-wave merge in the owner quad ----
    int jm;
    {
      float4 v = *(const float4*)&keybuf[it_o][kq][0];
      float s0 = v.x, s1 = v.y, s2 = v.z;
      {
        float b0k = __shfl_xor(s0, 1), b1k = __shfl_xor(s1, 1), b2k = __shfl_xor(s2, 1);
        mrg3(s0, s1, s2, b0k, b1k, b2k);
        b0k = __shfl_xor(s0, 2); b1k = __shfl_xor(s1, 2); b2k = __shfl_xor(s2, 2);
        mrg3(s0, s1, s2, b0k, b1k, b2k);
      }
      jm = (int)(__float_as_uint(s0) & 255u);
      const float gap = unpv(s1) - unpv(s0);   // d/2 scale
      if (gap < TAUH) {   // quad-uniform: exact fp32 rescore of top-3
        const int cand[3] = { jm, (int)(__float_as_uint(s1) & 255u),
                                  (int)(__float_as_uint(s2) & 255u) };
        float bestd = FMAXV; int bestj = 0;
#pragma unroll 1
        for (int cc = 0; cc < 3; ++cc) {
          const int j = cand[cc];
          const float* row = cbf32 + (size_t)j * ED + kq * 64;
          float p2 = 0.f;
#pragma unroll
          for (int i = 0; i < 16; ++i) {
            float4 q = *(const float4*)(row + 4 * i);
            p2 = fmaf(res[4 * i + 0], q.x, p2);
            p2 = fmaf(res[4 * i + 1], q.y, p2);
            p2 = fmaf(res[4 * i + 2], q.z, p2);
            p2 = fmaf(res[4 * i + 3], q.w, p2);
          }
          p2 += __shfl_xor(p2, 1);
          p2 += __shfl_xor(p2, 2);
          const float d = fmaf(-2.f, p2, nrm[j]);
          if (d < bestd || (d == bestd && j < bestj)) { bestd = d; bestj = j; }
        }
        jm = bestj;
      }
      if (kq == 0) {
        const size_t ioff = (br ? OFF_RIDX : OFF_SIDX) + (size_t)(b0 + it_o) * NQL + lev;
        out[ioff] = (float)jm;
      }
    }

    // ---- residual update + loss (exact reference rounding chain) ----
    {
      const float* crow = cbf32 + (size_t)jm * ED + kq * 64;
#pragma unroll
      for (int i = 0; i < 16; ++i) {
        float4 q = *(const float4*)(crow + 4 * i);
#pragma unroll
        for (int u = 0; u < 4; ++u) {
          float cv = (u == 0 ? q.x : u == 1 ? q.y : u == 2 ? q.z : q.w);
          float r  = res[4 * i + u];
          float dd = cv - r;
          if (u & 1) lossB = fmaf(dd, dd, lossB);   // 2 chains: break serial dep
          else       lossA = fmaf(dd, dd, lossA);
          float xr = r + dd;      // straight-through x_res
          res[4 * i + u] = r - xr;
        }
      }
    }
  }

  // ---- x_q = x - res_final ----
  {
    const float* xp = x + (size_t)(b0 + it_o) * (2 * ED) + br * ED + kq * 64;
    float* op = out + (br ? OFF_REC : 0) + (size_t)(b0 + it_o) * ED + kq * 64;
#pragma unroll
    for (int i = 0; i < 16; ++i) {
      float4 xv = *(const float4*)(xp + 4 * i);
      float4 o;
      o.x = xv.x - res[4 * i + 0];
      o.y = xv.y - res[4 * i + 1];
      o.z = xv.z - res[4 * i + 2];
      o.w = xv.w - res[4 * i + 3];
      *(float4*)(op + 4 * i) = o;
    }
  }

  // ---- loss: one wave-reduce + one atomic per block (8 slots) ----
  float lossReg = lossA + lossB;
#pragma unroll
  for (int d = 1; d < 64; d <<= 1) lossReg += __shfl_xor(lossReg, d);
  if (lane == 0) redS[w] = lossReg;
  __syncthreads();
  if (tid == 0)
    atomicAdd(&lossAcc[blockIdx.x & 7], (double)((redS[0] + redS[1]) + (redS[2] + redS[3])));
}

// ---- finalize scalar loss ----
__global__ void kFin(const double* __restrict__ lossAcc, float* __restrict__ out) {
  if (blockIdx.x == 0 && threadIdx.x == 0) {
    double s = 0.0;
    for (int l = 0; l < 8; ++l) s += lossAcc[l];
    out[OFF_LOSS] = (float)(s * 1.25 / ((double)NB * ED) / 8.0);
  }
}

extern "C" void kernel_launch(void* const* d_in, const int* in_sizes, int n_in,
                              void* d_out, int out_size, void* d_ws, size_t ws_size,
                              hipStream_t stream) {
  const float* x   = (const float*)d_in[0];
  const float* cbS = (const float*)d_in[1];
  const float* cbR = (const float*)d_in[2];
  float* out = (float*)d_out;
  char*  ws  = (char*)d_ws;

  double* lossAcc = (double*)(ws + WS_LOSS);
  float*  norms   = (float*)(ws + WS_NORM);
  f16*    cbH     = (f16*)(ws + WS_CBH);

  hipLaunchKernelGGL(kPrep,  dim3(8),    dim3(256), 0, stream, cbS, cbR, norms, lossAcc);
  hipLaunchKernelGGL(kConvH, dim3(2048), dim3(256), 0, stream, cbS, cbR, cbH);
  hipLaunchKernelGGL(kMain,  dim3(NB / 64, 2), dim3(256), 0, stream,
                     x, cbS, cbR, cbH, norms, lossAcc, out);
  hipLaunchKernelGGL(kFin,   dim3(1),    dim3(64),  0, stream, lossAcc, out);
}